// Round 1
// baseline (235.988 us; speedup 1.0000x reference)
//
#include <hip/hip_runtime.h>

#define FEAT_DIM 512
#define BATCH 256

// Phase 1: per-row stats, staged INSIDE the output buffer (no workspace).
//   out[row*512 + 0] = ||f_row - c_{y_row}||^2
//   out[row*512 + 1] = logsumexp(f_row)
// Kernel boundary orders these writes before phase-2 reads.
__global__ __launch_bounds__(64) void cl_rowstats(
    const float* __restrict__ feats,
    const float* __restrict__ centers,
    const int* __restrict__ labels,
    float* __restrict__ out) {
    const int row = blockIdx.x;          // 0..255
    const int lane = threadIdx.x;        // 0..63, one wave per row

    const float4* f4 = (const float4*)(feats + (size_t)row * FEAT_DIM);
    const int lbl = labels[row];
    const float4* c4 = (const float4*)(centers + (size_t)lbl * FEAT_DIM);

    float4 fa = f4[lane * 2];
    float4 fb = f4[lane * 2 + 1];
    float4 ca = c4[lane * 2];
    float4 cb = c4[lane * 2 + 1];

    float f[8] = {fa.x, fa.y, fa.z, fa.w, fb.x, fb.y, fb.z, fb.w};
    float c[8] = {ca.x, ca.y, ca.z, ca.w, cb.x, cb.y, cb.z, cb.w};

    float d = 0.f;
    float m = -INFINITY;
#pragma unroll
    for (int k = 0; k < 8; ++k) {
        float t = f[k] - c[k];
        d += t * t;
        m = fmaxf(m, f[k]);
    }

#pragma unroll
    for (int off = 32; off >= 1; off >>= 1) {
        d += __shfl_xor(d, off, 64);
        m = fmaxf(m, __shfl_xor(m, off, 64));
    }

    float s = 0.f;
#pragma unroll
    for (int k = 0; k < 8; ++k) s += __expf(f[k] - m);
#pragma unroll
    for (int off = 32; off >= 1; off >>= 1) s += __shfl_xor(s, off, 64);

    if (lane == 0) {
        out[(size_t)row * FEAT_DIM + 0] = d;
        out[(size_t)row * FEAT_DIM + 1] = m + __logf(s);
    }
}

// Phase 2: single block. total = sum(dist); out[r*512] = total - lse[r].
// Reduction order replicated bit-exactly from the previously-passing kernel
// (per-wave butterfly, then part[0]+part[1]+part[2]+part[3]).
__global__ __launch_bounds__(256) void cl_total(float* __restrict__ out) {
    const int tid = threadIdx.x;                 // 0..255 == row
    const float d = out[(size_t)tid * FEAT_DIM + 0];
    const float l = out[(size_t)tid * FEAT_DIM + 1];

    float v = d;
#pragma unroll
    for (int off = 32; off >= 1; off >>= 1) v += __shfl_xor(v, off, 64);

    __shared__ float part[4];
    if ((tid & 63) == 0) part[tid >> 6] = v;
    __syncthreads();
    const float total = part[0] + part[1] + part[2] + part[3];

    out[(size_t)tid * FEAT_DIM] = total - l;     // add-value for this row
}

// Phase 3: block b owns rows 2b and 2b+1 completely (256 float4 = 1024 floats).
// Read the two add-values (in-block, pre-sync), then overwrite with feats+add.
__global__ __launch_bounds__(256) void cl_write(
    const float* __restrict__ feats,
    float* __restrict__ out) {
    const int tid = threadIdx.x;                 // 0..255
    const int b = blockIdx.x;                    // 0..127

    __shared__ float addsh[2];
    if (tid < 2) addsh[tid] = out[(size_t)(2 * b + tid) * FEAT_DIM];
    __syncthreads();

    const int idx = b * 256 + tid;               // float4 index, 0..32767
    const float add = addsh[tid >> 7];           // row 2b for tid<128, else 2b+1

    float4 f = ((const float4*)feats)[idx];
    float4 o;
    o.x = f.x + add;
    o.y = f.y + add;
    o.z = f.z + add;
    o.w = f.w + add;
    ((float4*)out)[idx] = o;
}

extern "C" void kernel_launch(void* const* d_in, const int* in_sizes, int n_in,
                              void* d_out, int out_size, void* d_ws, size_t ws_size,
                              hipStream_t stream) {
    const float* feats   = (const float*)d_in[0];
    const float* centers = (const float*)d_in[1];
    const int*   labels  = (const int*)d_in[2];
    float* out = (float*)d_out;

    (void)d_ws; (void)ws_size;   // workspace intentionally untouched

    cl_rowstats<<<BATCH, 64, 0, stream>>>(feats, centers, labels, out);
    cl_total<<<1, 256, 0, stream>>>(out);
    cl_write<<<BATCH * FEAT_DIM / 4 / 256, 256, 0, stream>>>(feats, out);
}